// Round 2
// baseline (147.380 us; speedup 1.0000x reference)
//
#include <hip/hip_runtime.h>
#include <cstdint>

#define E_EDGES 400000
#define N_NODES 25000
#define GROUPS  (E_EDGES/16)   // 25000

typedef float f32x4 __attribute__((ext_vector_type(4)));
typedef __bf16 bf16x8 __attribute__((ext_vector_type(8)));

static __device__ __forceinline__ ushort f2bf(float f) {
    union { __bf16 b; ushort u; } c; c.b = (__bf16)f; return c.u;
}

// ---------------------------------------------------------------------------
// K_hist: histogram of dst (uint counters) ; low threads also pack W2/b2 into
// bf16 MFMA fragment order [kt:17][nt:2][kg:4][ln:16][j:8].
// ---------------------------------------------------------------------------
__global__ void __launch_bounds__(256) k_hist(const int* __restrict__ ei,
                                              uint* __restrict__ cnt_u,
                                              const float* __restrict__ W2,
                                              const float* __restrict__ b2,
                                              ushort* __restrict__ packed) {
    int t = blockIdx.x * 256 + threadIdx.x;
    if (t < 17 * 2 * 4 * 16 * 8) {
        int j  = t & 7;
        int ln = (t >> 3) & 15;
        int kg = (t >> 7) & 3;
        int nt = (t >> 9) & 1;
        int kt = t >> 10;
        int kap = kg * 8 + j;
        float v = 0.0f;
        if (kt < 16)       v = W2[kap * 512 + kt * 32 + nt * 16 + ln];
        else if (kap < 16) v = b2[kap * 32 + nt * 16 + ln];
        packed[t] = f2bf(v);
    }
    if (t < E_EDGES) atomicAdd(&cnt_u[ei[E_EDGES + t]], 1u);
}

// ---------------------------------------------------------------------------
// K_scan: single-block exclusive scan of 25000 counts -> ofs[25001] (+ copy)
// ---------------------------------------------------------------------------
__global__ void __launch_bounds__(1024) k_scan(const uint* __restrict__ cnt_u,
                                               uint* __restrict__ ofs,
                                               uint* __restrict__ ofs_work) {
    const int t = threadIdx.x;
    const int B = 25;                     // 1024*25 = 25600 >= 25000
    uint loc[B];
    uint s = 0;
    const int base = t * B;
#pragma unroll
    for (int k = 0; k < B; ++k) {
        int i = base + k;
        uint v = (i < N_NODES) ? cnt_u[i] : 0u;
        loc[k] = s; s += v;
    }
    const int lane = t & 63;
    uint incl = s;
#pragma unroll
    for (int off = 1; off < 64; off <<= 1) {
        uint u = __shfl_up(incl, off, 64);
        if (lane >= off) incl += u;
    }
    __shared__ uint wsum[16], wpre[16];
    const int wid = t >> 6;
    if (lane == 63) wsum[wid] = incl;
    __syncthreads();
    if (t == 0) { uint c = 0; for (int w = 0; w < 16; ++w) { wpre[w] = c; c += wsum[w]; } }
    __syncthreads();
    const uint thr_excl = incl - s + wpre[wid];
#pragma unroll
    for (int k = 0; k < B; ++k) {
        int i = base + k;
        if (i < N_NODES) { uint e = thr_excl + loc[k]; ofs[i] = e; ofs_work[i] = e; }
    }
    if (t == 1023) ofs[N_NODES] = thr_excl + s;
}

// ---------------------------------------------------------------------------
// K_perm: scatter edges into dst-sorted order. Moves ea rows so the edge
// kernel reads everything coalesced (no eperm gather chain).
// ---------------------------------------------------------------------------
__global__ void __launch_bounds__(256) k_perm(const int* __restrict__ ei,
                                              const float* __restrict__ ea,
                                              uint* __restrict__ ofs_work,
                                              float* __restrict__ ea_s,
                                              int* __restrict__ src_s,
                                              int* __restrict__ dst_s) {
    int e = blockIdx.x * 256 + threadIdx.x;
    if (e >= E_EDGES) return;
    int d = ei[E_EDGES + e];
    uint r = atomicAdd(&ofs_work[d], 1u);
    const f32x4* ap = (const f32x4*)(ea + (size_t)e * 8);
    f32x4 a0 = ap[0], a1 = ap[1];
    f32x4* op = (f32x4*)(ea_s + (size_t)r * 8);
    op[0] = a0; op[1] = a1;
    src_s[r] = ei[e];
    dst_s[r] = d;
}

// ---------------------------------------------------------------------------
// K_edge2: fused edge MLP + GEMM + run-merged scatter, over dst-sorted edges.
// msg[16e x 32o] = A'[16e x 544] @ W2'[544 x 32]; A' built in registers.
// ---------------------------------------------------------------------------
__global__ void __launch_bounds__(256) k_edge2(const float* __restrict__ ea_s,
                                               const float* __restrict__ x,
                                               const int* __restrict__ src_s,
                                               const int* __restrict__ dst_s,
                                               const ushort* __restrict__ packed,
                                               const float* __restrict__ W1,
                                               const float* __restrict__ b1,
                                               float* __restrict__ agg) {
    __shared__ alignas(16) ushort w2l[17408];
    __shared__ alignas(16) float w1l[256];   // 8 x 32
    __shared__ float b1l[32];
    {
        const uint4* s = (const uint4*)packed;
        uint4* d = (uint4*)w2l;
        for (int i = threadIdx.x; i < 2176; i += 256) d[i] = s[i];
        if (threadIdx.x < 256) w1l[threadIdx.x] = W1[threadIdx.x];
        if (threadIdx.x < 32)  b1l[threadIdx.x] = b1[threadIdx.x];
    }
    __syncthreads();

    const int lane = threadIdx.x & 63;
    const int ln = lane & 15;       // A row (edge in group) / B col (output)
    const int kg = lane >> 4;       // k-group
    const int gw = blockIdx.x * 4 + (threadIdx.x >> 6);

    for (int g = gw; g < GROUPS; g += gridDim.x * 4) {
        const int g16 = g * 16;
        const int e = g16 + ln;
        const int srcn = src_s[e];

        // edge-attr row (8 f32), already in sorted order -> coalesced
        const f32x4* ep = (const f32x4*)(ea_s + (size_t)e * 8);
        const f32x4 ea0 = ep[0], ea1 = ep[1];

        // h[m] for m = 8*kg + j, j=0..7  (edge MLP hidden, in-register)
        float hf[8];
#pragma unroll
        for (int j = 0; j < 8; ++j) hf[j] = b1l[8 * kg + j];
#pragma unroll
        for (int k = 0; k < 8; ++k) {
            const float av = (k < 4) ? ea0[k] : ea1[k - 4];
            const f32x4* wr = (const f32x4*)(&w1l[k * 32 + 8 * kg]);
            const f32x4 w0 = wr[0], w1v = wr[1];
            hf[0] += av * w0[0]; hf[1] += av * w0[1];
            hf[2] += av * w0[2]; hf[3] += av * w0[3];
            hf[4] += av * w1v[0]; hf[5] += av * w1v[1];
            hf[6] += av * w1v[2]; hf[7] += av * w1v[3];
        }
#pragma unroll
        for (int j = 0; j < 8; ++j) hf[j] = fmaxf(hf[j], 0.0f);

        // x row of my edge (16 f32)
        const f32x4* xp = (const f32x4*)(x + (size_t)srcn * 16);
        const f32x4 xq0 = xp[0], xq1 = xp[1], xq2 = xp[2], xq3 = xp[3];
        float xr[16];
        xr[0]=xq0[0]; xr[1]=xq0[1]; xr[2]=xq0[2]; xr[3]=xq0[3];
        xr[4]=xq1[0]; xr[5]=xq1[1]; xr[6]=xq1[2]; xr[7]=xq1[3];
        xr[8]=xq2[0]; xr[9]=xq2[1]; xr[10]=xq2[2]; xr[11]=xq2[3];
        xr[12]=xq3[0]; xr[13]=xq3[1]; xr[14]=xq3[2]; xr[15]=xq3[3];

        f32x4 acc0 = {0.f, 0.f, 0.f, 0.f};
        f32x4 acc1 = {0.f, 0.f, 0.f, 0.f};

#pragma unroll
        for (int kt = 0; kt < 16; ++kt) {
            const float xv = xr[kt];
            bf16x8 a;
#pragma unroll
            for (int j = 0; j < 8; ++j) a[j] = (__bf16)(xv * hf[j]);
            const bf16x8 b0  = *(const bf16x8*)(&w2l[(kt * 2 + 0) * 512 + lane * 8]);
            const bf16x8 b1v = *(const bf16x8*)(&w2l[(kt * 2 + 1) * 512 + lane * 8]);
            acc0 = __builtin_amdgcn_mfma_f32_16x16x32_bf16(a, b0,  acc0, 0, 0, 0);
            acc1 = __builtin_amdgcn_mfma_f32_16x16x32_bf16(a, b1v, acc1, 0, 0, 0);
        }
        { // 17th K-tile folds b2:  A = x (zero-padded past i=16), B = b2 tile
            bf16x8 a;
            if (kg == 0) {
                a[0]=(__bf16)xq0[0]; a[1]=(__bf16)xq0[1]; a[2]=(__bf16)xq0[2]; a[3]=(__bf16)xq0[3];
                a[4]=(__bf16)xq1[0]; a[5]=(__bf16)xq1[1]; a[6]=(__bf16)xq1[2]; a[7]=(__bf16)xq1[3];
            } else if (kg == 1) {
                a[0]=(__bf16)xq2[0]; a[1]=(__bf16)xq2[1]; a[2]=(__bf16)xq2[2]; a[3]=(__bf16)xq2[3];
                a[4]=(__bf16)xq3[0]; a[5]=(__bf16)xq3[1]; a[6]=(__bf16)xq3[2]; a[7]=(__bf16)xq3[3];
            } else {
                a[0]=a[1]=a[2]=a[3]=a[4]=a[5]=a[6]=a[7]=(__bf16)0.0f;
            }
            const bf16x8 b0  = *(const bf16x8*)(&w2l[(16 * 2 + 0) * 512 + lane * 8]);
            const bf16x8 b1v = *(const bf16x8*)(&w2l[(16 * 2 + 1) * 512 + lane * 8]);
            acc0 = __builtin_amdgcn_mfma_f32_16x16x32_bf16(a, b0,  acc0, 0, 0, 0);
            acc1 = __builtin_amdgcn_mfma_f32_16x16x32_bf16(a, b1v, acc1, 0, 0, 0);
        }

        // run-merged scatter: my 4 C-rows (edges g16+kg*4+j) have sorted dsts
        const int rbase = g16 + kg * 4;
        const int d0 = dst_s[rbase + 0];
        const int d1 = dst_s[rbase + 1];
        const int d2 = dst_s[rbase + 2];
        const int d3 = dst_s[rbase + 3];
        int cur = d0;
        float s0 = acc0[0], s1 = acc1[0];
        if (d1 == cur) { s0 += acc0[1]; s1 += acc1[1]; }
        else { atomicAdd(&agg[cur*32+ln], s0); atomicAdd(&agg[cur*32+16+ln], s1);
               cur = d1; s0 = acc0[1]; s1 = acc1[1]; }
        if (d2 == cur) { s0 += acc0[2]; s1 += acc1[2]; }
        else { atomicAdd(&agg[cur*32+ln], s0); atomicAdd(&agg[cur*32+16+ln], s1);
               cur = d2; s0 = acc0[2]; s1 = acc1[2]; }
        if (d3 == cur) { s0 += acc0[3]; s1 += acc1[3]; }
        else { atomicAdd(&agg[cur*32+ln], s0); atomicAdd(&agg[cur*32+16+ln], s1);
               cur = d3; s0 = acc0[3]; s1 = acc1[3]; }
        atomicAdd(&agg[cur*32+ln], s0); atomicAdd(&agg[cur*32+16+ln], s1);
    }
}

// ---------------------------------------------------------------------------
// K_node: fused  a = relu(agg/cnt + x@root + bias)  then  out = a@Wlin + blin
// 8 nodes per block via LDS.
// ---------------------------------------------------------------------------
__global__ void __launch_bounds__(256) k_node(const float* __restrict__ agg,
                                              const uint* __restrict__ ofs,
                                              const float* __restrict__ x,
                                              const float* __restrict__ root,
                                              const float* __restrict__ bias,
                                              const float* __restrict__ Wlin,
                                              const float* __restrict__ blin,
                                              float* __restrict__ out) {
    __shared__ float al[256];
    const int n0 = blockIdx.x * 8;
    const int t = threadIdx.x;
    const int n = n0 + (t >> 5), h = t & 31;
    float a = 0.0f;
    if (n < N_NODES) {
        const float c = (float)(ofs[n + 1] - ofs[n]);
        float s = agg[n * 32 + h] / fmaxf(c, 1.0f) + bias[h];
        const f32x4* xp = (const f32x4*)(x + (size_t)n * 16);
        const f32x4 x0 = xp[0], x1 = xp[1], x2 = xp[2], x3 = xp[3];
        float xv[16];
        xv[0]=x0[0]; xv[1]=x0[1]; xv[2]=x0[2]; xv[3]=x0[3];
        xv[4]=x1[0]; xv[5]=x1[1]; xv[6]=x1[2]; xv[7]=x1[3];
        xv[8]=x2[0]; xv[9]=x2[1]; xv[10]=x2[2]; xv[11]=x2[3];
        xv[12]=x3[0]; xv[13]=x3[1]; xv[14]=x3[2]; xv[15]=x3[3];
#pragma unroll
        for (int i = 0; i < 16; ++i) s += xv[i] * root[i * 32 + h];
        a = fmaxf(s, 0.0f);
    }
    al[t] = a;
    __syncthreads();
    if (t < 128) {
        const int nj = n0 + (t >> 4), j = t & 15;
        if (nj < N_NODES) {
            float s = blin[j];
#pragma unroll
            for (int h2 = 0; h2 < 32; ++h2) s += al[(t >> 4) * 32 + h2] * Wlin[h2 * 16 + j];
            out[nj * 16 + j] = s;
        }
    }
}

// ---------------------------------------------------------------------------
extern "C" void kernel_launch(void* const* d_in, const int* in_sizes, int n_in,
                              void* d_out, int out_size, void* d_ws, size_t ws_size,
                              hipStream_t stream) {
    const float* x    = (const float*)d_in[0];
    const float* ea   = (const float*)d_in[1];
    const float* W1   = (const float*)d_in[2];
    const float* b1   = (const float*)d_in[3];
    const float* W2   = (const float*)d_in[4];
    const float* b2   = (const float*)d_in[5];
    const float* root = (const float*)d_in[6];
    const float* bias = (const float*)d_in[7];
    const float* Wlin = (const float*)d_in[8];
    const float* blin = (const float*)d_in[9];
    const int*   ei   = (const int*)d_in[10];
    float* out = (float*)d_out;

    char* ws = (char*)d_ws;
    float*  agg      = (float*)(ws + 0);            // 3,200,000
    uint*   cnt_u    = (uint*)(ws + 3200000);       //   100,000
    uint*   ofs      = (uint*)(ws + 3300000);       //   100,004
    uint*   ofs_work = (uint*)(ws + 3400032);       //   100,000
    float*  ea_s     = (float*)(ws + 3500032);      // 12,800,000
    int*    src_s    = (int*)(ws + 16300032);       //  1,600,000
    int*    dst_s    = (int*)(ws + 17900032);       //  1,600,000
    ushort* packed   = (ushort*)(ws + 19500032);    //     34,816

    hipMemsetAsync(d_ws, 0, 3300000, stream);       // agg + cnt_u

    k_hist<<<(E_EDGES + 255) / 256, 256, 0, stream>>>(ei, cnt_u, W2, b2, packed);
    k_scan<<<1, 1024, 0, stream>>>(cnt_u, ofs, ofs_work);
    k_perm<<<(E_EDGES + 255) / 256, 256, 0, stream>>>(ei, ea, ofs_work, ea_s, src_s, dst_s);
    k_edge2<<<1024, 256, 0, stream>>>(ea_s, x, src_s, dst_s, packed, W1, b1, agg);
    k_node<<<(N_NODES + 7) / 8, 256, 0, stream>>>(agg, ofs, x, root, bias, Wlin, blin, out);
}

// Round 3
// 86.082 us; speedup vs baseline: 1.7121x; 1.7121x over previous
//
#include <hip/hip_runtime.h>
#include <cstdint>

#define E_EDGES 400000
#define N_NODES 25000
#define GROUPS  (E_EDGES/16)   // 25000
#define NPACK   18432          // ushorts: 17 K-tiles (17408) + 2 W1^T A-frags (1024)

typedef float f32x4 __attribute__((ext_vector_type(4)));
typedef __bf16 bf16x8 __attribute__((ext_vector_type(8)));

static __device__ __forceinline__ ushort f2bf(float f) {
    union { __bf16 b; ushort u; } c; c.b = (__bf16)f; return c.u;
}

// ---------------------------------------------------------------------------
// K_pack: W2 (+b2 17th K-tile) into MFMA B-frag order with kap remap,
// plus W1^T packed as two A-frags for the h-MFMA.
// kap(kg,j) = j<4 ? 4kg+j : 16+4kg+(j-4)   (matches h-MFMA C layout)
// ---------------------------------------------------------------------------
__global__ void __launch_bounds__(256) k_pack(const float* __restrict__ W2,
                                              const float* __restrict__ b2,
                                              const float* __restrict__ W1,
                                              ushort* __restrict__ packed) {
    int t = blockIdx.x * 256 + threadIdx.x;
    if (t >= NPACK) return;
    float v = 0.0f;
    if (t < 17408) {
        int j  = t & 7;
        int ln = (t >> 3) & 15;
        int kg = (t >> 7) & 3;
        int nt = (t >> 9) & 1;
        int kt = t >> 10;
        int kap = (j < 4) ? (kg * 4 + j) : (16 + kg * 4 + (j - 4));
        if (kt < 16)       v = W2[kap * 512 + kt * 32 + nt * 16 + ln];
        else if (kap < 16) v = b2[kap * 32 + nt * 16 + ln];
    } else {
        int idx  = t - 17408;
        int half = idx >> 9;          // 0: m=0..15, 1: m=16..31
        int lane = (idx >> 3) & 63;
        int j    = idx & 7;
        int kg = lane >> 4, ln = lane & 15;
        if (kg == 0) v = W1[j * 32 + half * 16 + ln];   // A[row=m=ln][k=j] = W1[j][m]
    }
    packed[t] = f2bf(v);
}

// ---------------------------------------------------------------------------
// K_edge: 2 groups (32 edges) per wave, fully fused:
//   h = relu(ea@W1+b1) via 2 MFMAs/group (in-register C -> A'-build directly)
//   msg = A'[16e x 544] @ W2'[544 x 32] via 17 K-tiles x 2 N-tiles
//   atomic scatter to agg + predicated cnt atomics.
// Exact grid: 3125 blocks x 4 waves x 2 groups = 25000 groups. No loop.
// ---------------------------------------------------------------------------
__global__ void __launch_bounds__(256, 4) k_edge(const float* __restrict__ ea,
                                                 const float* __restrict__ x,
                                                 const int* __restrict__ ei,
                                                 const ushort* __restrict__ packed,
                                                 const float* __restrict__ b1,
                                                 float* __restrict__ agg,
                                                 uint* __restrict__ cnt_u) {
    __shared__ alignas(16) ushort w2l[NPACK];
    __shared__ float b1l[32];
    {
        const uint4* s = (const uint4*)packed;
        uint4* d = (uint4*)w2l;
        for (int i = threadIdx.x; i < NPACK / 8; i += 256) d[i] = s[i];
        if (threadIdx.x < 32) b1l[threadIdx.x] = b1[threadIdx.x];
    }
    __syncthreads();

    const int lane = threadIdx.x & 63;
    const int ln = lane & 15;
    const int kg = lane >> 4;
    const int gp = blockIdx.x * 4 + (threadIdx.x >> 6);
    const int g0 = gp * 2, g1 = g0 + 1;
    const int e0 = g0 * 16 + ln, e1 = g1 * 16 + ln;

    // issue all index loads early
    const int s0  = ei[e0],            s1  = ei[e1];
    const int dc0 = ei[E_EDGES + e0],  dc1 = ei[E_EDGES + e1];
    const int r0 = g0 * 16 + kg * 4, r1 = g1 * 16 + kg * 4;
    const int d00 = ei[E_EDGES + r0 + 0], d01 = ei[E_EDGES + r0 + 1];
    const int d02 = ei[E_EDGES + r0 + 2], d03 = ei[E_EDGES + r0 + 3];
    const int d10 = ei[E_EDGES + r1 + 0], d11 = ei[E_EDGES + r1 + 1];
    const int d12 = ei[E_EDGES + r1 + 2], d13 = ei[E_EDGES + r1 + 3];

    // x gathers (both groups, in flight together)
    const f32x4* xp0 = (const f32x4*)(x + (size_t)s0 * 16);
    const f32x4 xa0 = xp0[0], xa1 = xp0[1], xa2 = xp0[2], xa3 = xp0[3];
    const f32x4* xp1 = (const f32x4*)(x + (size_t)s1 * 16);
    const f32x4 xb0 = xp1[0], xb1 = xp1[1], xb2 = xp1[2], xb3 = xp1[3];

    // ea rows (lane's own edge; broadcast across kg quartets)
    const f32x4* ep0 = (const f32x4*)(ea + (size_t)e0 * 8);
    const f32x4 ea00 = ep0[0], ea01 = ep0[1];
    const f32x4* ep1 = (const f32x4*)(ea + (size_t)e1 * 8);
    const f32x4 ea10 = ep1[0], ea11 = ep1[1];

    // B-frag for h-MFMA: k = 8*kg+j valid only for kg==0
    bf16x8 eb0, eb1;
    if (kg == 0) {
        eb0[0]=(__bf16)ea00[0]; eb0[1]=(__bf16)ea00[1]; eb0[2]=(__bf16)ea00[2]; eb0[3]=(__bf16)ea00[3];
        eb0[4]=(__bf16)ea01[0]; eb0[5]=(__bf16)ea01[1]; eb0[6]=(__bf16)ea01[2]; eb0[7]=(__bf16)ea01[3];
        eb1[0]=(__bf16)ea10[0]; eb1[1]=(__bf16)ea10[1]; eb1[2]=(__bf16)ea10[2]; eb1[3]=(__bf16)ea10[3];
        eb1[4]=(__bf16)ea11[0]; eb1[5]=(__bf16)ea11[1]; eb1[6]=(__bf16)ea11[2]; eb1[7]=(__bf16)ea11[3];
    } else {
        const __bf16 z = (__bf16)0.0f;
        eb0[0]=z; eb0[1]=z; eb0[2]=z; eb0[3]=z; eb0[4]=z; eb0[5]=z; eb0[6]=z; eb0[7]=z;
        eb1 = eb0;
    }

    // h via MFMA: C[row=m-part][col=e=ln]; lane gets h[m=4kg+r] and h[m=16+4kg+r]
    const bf16x8 aw0 = *(const bf16x8*)(&w2l[17408 + lane * 8]);
    const bf16x8 aw1 = *(const bf16x8*)(&w2l[17408 + 512 + lane * 8]);
    f32x4 z4 = {0.f, 0.f, 0.f, 0.f};
    f32x4 hA0 = __builtin_amdgcn_mfma_f32_16x16x32_bf16(aw0, eb0, z4, 0, 0, 0);
    f32x4 hA1 = __builtin_amdgcn_mfma_f32_16x16x32_bf16(aw1, eb0, z4, 0, 0, 0);
    f32x4 hB0 = __builtin_amdgcn_mfma_f32_16x16x32_bf16(aw0, eb1, z4, 0, 0, 0);
    f32x4 hB1 = __builtin_amdgcn_mfma_f32_16x16x32_bf16(aw1, eb1, z4, 0, 0, 0);

    float h0[8], h1[8];
#pragma unroll
    for (int r = 0; r < 4; ++r) {
        const float blo = b1l[4 * kg + r], bhi = b1l[16 + 4 * kg + r];
        h0[r]     = fmaxf(hA0[r] + blo, 0.f);
        h0[4 + r] = fmaxf(hA1[r] + bhi, 0.f);
        h1[r]     = fmaxf(hB0[r] + blo, 0.f);
        h1[4 + r] = fmaxf(hB1[r] + bhi, 0.f);
    }

    float xr0[16], xr1[16];
    xr0[0]=xa0[0]; xr0[1]=xa0[1]; xr0[2]=xa0[2]; xr0[3]=xa0[3];
    xr0[4]=xa1[0]; xr0[5]=xa1[1]; xr0[6]=xa1[2]; xr0[7]=xa1[3];
    xr0[8]=xa2[0]; xr0[9]=xa2[1]; xr0[10]=xa2[2]; xr0[11]=xa2[3];
    xr0[12]=xa3[0]; xr0[13]=xa3[1]; xr0[14]=xa3[2]; xr0[15]=xa3[3];
    xr1[0]=xb0[0]; xr1[1]=xb0[1]; xr1[2]=xb0[2]; xr1[3]=xb0[3];
    xr1[4]=xb1[0]; xr1[5]=xb1[1]; xr1[6]=xb1[2]; xr1[7]=xb1[3];
    xr1[8]=xb2[0]; xr1[9]=xb2[1]; xr1[10]=xb2[2]; xr1[11]=xb2[3];
    xr1[12]=xb3[0]; xr1[13]=xb3[1]; xr1[14]=xb3[2]; xr1[15]=xb3[3];

    f32x4 acc00 = z4, acc01 = z4, acc10 = z4, acc11 = z4;

#pragma unroll
    for (int kt = 0; kt < 16; ++kt) {
        const bf16x8 bf0 = *(const bf16x8*)(&w2l[(kt * 2 + 0) * 512 + lane * 8]);
        const bf16x8 bf1 = *(const bf16x8*)(&w2l[(kt * 2 + 1) * 512 + lane * 8]);
        const float xv0 = xr0[kt], xv1 = xr1[kt];
        bf16x8 a0, a1;
#pragma unroll
        for (int j = 0; j < 8; ++j) {
            a0[j] = (__bf16)(xv0 * h0[j]);
            a1[j] = (__bf16)(xv1 * h1[j]);
        }
        acc00 = __builtin_amdgcn_mfma_f32_16x16x32_bf16(a0, bf0, acc00, 0, 0, 0);
        acc10 = __builtin_amdgcn_mfma_f32_16x16x32_bf16(a1, bf0, acc10, 0, 0, 0);
        acc01 = __builtin_amdgcn_mfma_f32_16x16x32_bf16(a0, bf1, acc01, 0, 0, 0);
        acc11 = __builtin_amdgcn_mfma_f32_16x16x32_bf16(a1, bf1, acc11, 0, 0, 0);
    }
    { // 17th K-tile folds b2: a[j<4] = x[4kg+j], a[j>=4] = 0 (kap>=16 rows are zero)
        const f32x4 xs0 = (kg == 0) ? xa0 : ((kg == 1) ? xa1 : ((kg == 2) ? xa2 : xa3));
        const f32x4 xs1 = (kg == 0) ? xb0 : ((kg == 1) ? xb1 : ((kg == 2) ? xb2 : xb3));
        const __bf16 z = (__bf16)0.0f;
        bf16x8 a0, a1;
        a0[0]=(__bf16)xs0[0]; a0[1]=(__bf16)xs0[1]; a0[2]=(__bf16)xs0[2]; a0[3]=(__bf16)xs0[3];
        a0[4]=z; a0[5]=z; a0[6]=z; a0[7]=z;
        a1[0]=(__bf16)xs1[0]; a1[1]=(__bf16)xs1[1]; a1[2]=(__bf16)xs1[2]; a1[3]=(__bf16)xs1[3];
        a1[4]=z; a1[5]=z; a1[6]=z; a1[7]=z;
        const bf16x8 bf0 = *(const bf16x8*)(&w2l[(16 * 2 + 0) * 512 + lane * 8]);
        const bf16x8 bf1 = *(const bf16x8*)(&w2l[(16 * 2 + 1) * 512 + lane * 8]);
        acc00 = __builtin_amdgcn_mfma_f32_16x16x32_bf16(a0, bf0, acc00, 0, 0, 0);
        acc10 = __builtin_amdgcn_mfma_f32_16x16x32_bf16(a1, bf0, acc10, 0, 0, 0);
        acc01 = __builtin_amdgcn_mfma_f32_16x16x32_bf16(a0, bf1, acc01, 0, 0, 0);
        acc11 = __builtin_amdgcn_mfma_f32_16x16x32_bf16(a1, bf1, acc11, 0, 0, 0);
    }

    // scatter: C row r = edge g*16 + kg*4 + r ; cols ln / 16+ln
    atomicAdd(&agg[d00 * 32 + ln], acc00[0]);
    atomicAdd(&agg[d01 * 32 + ln], acc00[1]);
    atomicAdd(&agg[d02 * 32 + ln], acc00[2]);
    atomicAdd(&agg[d03 * 32 + ln], acc00[3]);
    atomicAdd(&agg[d00 * 32 + 16 + ln], acc01[0]);
    atomicAdd(&agg[d01 * 32 + 16 + ln], acc01[1]);
    atomicAdd(&agg[d02 * 32 + 16 + ln], acc01[2]);
    atomicAdd(&agg[d03 * 32 + 16 + ln], acc01[3]);
    atomicAdd(&agg[d10 * 32 + ln], acc10[0]);
    atomicAdd(&agg[d11 * 32 + ln], acc10[1]);
    atomicAdd(&agg[d12 * 32 + ln], acc10[2]);
    atomicAdd(&agg[d13 * 32 + ln], acc10[3]);
    atomicAdd(&agg[d10 * 32 + 16 + ln], acc11[0]);
    atomicAdd(&agg[d11 * 32 + 16 + ln], acc11[1]);
    atomicAdd(&agg[d12 * 32 + 16 + ln], acc11[2]);
    atomicAdd(&agg[d13 * 32 + 16 + ln], acc11[3]);

    if (kg == 0) {
        atomicAdd(&cnt_u[dc0], 1u);
        atomicAdd(&cnt_u[dc1], 1u);
    }
}

// ---------------------------------------------------------------------------
// K_node: fused  a = relu(agg/cnt + x@root + bias)  then  out = a@Wlin + blin
// ---------------------------------------------------------------------------
__global__ void __launch_bounds__(256) k_node(const float* __restrict__ agg,
                                              const uint* __restrict__ cnt_u,
                                              const float* __restrict__ x,
                                              const float* __restrict__ root,
                                              const float* __restrict__ bias,
                                              const float* __restrict__ Wlin,
                                              const float* __restrict__ blin,
                                              float* __restrict__ out) {
    __shared__ float al[256];
    const int n0 = blockIdx.x * 8;
    const int t = threadIdx.x;
    const int n = n0 + (t >> 5), h = t & 31;
    float a = 0.0f;
    if (n < N_NODES) {
        const float c = (float)cnt_u[n];
        float s = agg[n * 32 + h] / fmaxf(c, 1.0f) + bias[h];
        const f32x4* xp = (const f32x4*)(x + (size_t)n * 16);
        const f32x4 x0 = xp[0], x1 = xp[1], x2 = xp[2], x3 = xp[3];
        float xv[16];
        xv[0]=x0[0]; xv[1]=x0[1]; xv[2]=x0[2]; xv[3]=x0[3];
        xv[4]=x1[0]; xv[5]=x1[1]; xv[6]=x1[2]; xv[7]=x1[3];
        xv[8]=x2[0]; xv[9]=x2[1]; xv[10]=x2[2]; xv[11]=x2[3];
        xv[12]=x3[0]; xv[13]=x3[1]; xv[14]=x3[2]; xv[15]=x3[3];
#pragma unroll
        for (int i = 0; i < 16; ++i) s += xv[i] * root[i * 32 + h];
        a = fmaxf(s, 0.0f);
    }
    al[t] = a;
    __syncthreads();
    if (t < 128) {
        const int nj = n0 + (t >> 4), j = t & 15;
        if (nj < N_NODES) {
            float s = blin[j];
#pragma unroll
            for (int h2 = 0; h2 < 32; ++h2) s += al[(t >> 4) * 32 + h2] * Wlin[h2 * 16 + j];
            out[nj * 16 + j] = s;
        }
    }
}

// ---------------------------------------------------------------------------
extern "C" void kernel_launch(void* const* d_in, const int* in_sizes, int n_in,
                              void* d_out, int out_size, void* d_ws, size_t ws_size,
                              hipStream_t stream) {
    const float* x    = (const float*)d_in[0];
    const float* ea   = (const float*)d_in[1];
    const float* W1   = (const float*)d_in[2];
    const float* b1   = (const float*)d_in[3];
    const float* W2   = (const float*)d_in[4];
    const float* b2   = (const float*)d_in[5];
    const float* root = (const float*)d_in[6];
    const float* bias = (const float*)d_in[7];
    const float* Wlin = (const float*)d_in[8];
    const float* blin = (const float*)d_in[9];
    const int*   ei   = (const int*)d_in[10];
    float* out = (float*)d_out;

    char* ws = (char*)d_ws;
    float*  agg    = (float*)(ws + 0);           // 3,200,000
    uint*   cnt_u  = (uint*)(ws + 3200000);      //   100,000
    ushort* packed = (ushort*)(ws + 3300000);    //    36,864

    hipMemsetAsync(d_ws, 0, 3300000, stream);    // agg + cnt_u

    k_pack<<<(NPACK + 255) / 256, 256, 0, stream>>>(W2, b2, W1, packed);
    k_edge<<<3125, 256, 0, stream>>>(ea, x, ei, packed, b1, agg, cnt_u);
    k_node<<<3125, 256, 0, stream>>>(agg, cnt_u, x, root, bias, Wlin, blin, out);
}